// Round 4
// baseline (174.840 us; speedup 1.0000x reference)
//
#include <hip/hip_runtime.h>

#define BATCH 256
#define SEQ   256
#define CDIM  384
#define HDIM  64

typedef __attribute__((ext_vector_type(8))) short bf16x8;
typedef __attribute__((ext_vector_type(4))) float f32x4;

__device__ __forceinline__ unsigned f2bf(float f) {
  union { float f; unsigned u; } v; v.f = f;
  unsigned r = v.u + 0x7FFFu + ((v.u >> 16) & 1u);   // RNE
  return r >> 16;
}

// ---------------------------------------------------------------------------
// kernel 0 (unchanged): WTf = [Wq|Wk|Wv]^T in MFMA fragment order.
//   frag record (ks,nt) = 64 lanes x 16 B; lane (ln15 + 16*quad) holds
//   WT row (nt*16+ln15), cols ks*32+quad*8 .. +7.
// ---------------------------------------------------------------------------
__global__ void wtrans_kernel(const float* __restrict__ Wk, const float* __restrict__ Wq,
                              const float* __restrict__ Wv, unsigned short* __restrict__ WTf) {
  int gid = blockIdx.x * 256 + threadIdx.x;
  if (gid >= 192 * CDIM) return;
  int n = gid / CDIM, kk = gid - n * CDIM;
  const float* W = (n < 64) ? Wq : (n < 128) ? Wk : Wv;
  int nt = n >> 4, ln = n & 15, ks = kk >> 5, sub = (kk >> 3) & 3, j = kk & 7;
  int lane = ln + 16 * sub;
  WTf[(((size_t)ks * 12 + nt) * 64 + lane) * 8 + j] =
      (unsigned short)f2bf(W[kk * HDIM + (n & 63)]);
}

// ---------------------------------------------------------------------------
// kernel 1: fused proj+attention, MAX-DEPTH x pipeline.
//   Round-7 post-mortem: counted-vmcnt overlap cut fused to ~56 us, but
//   Little's law says the x stream runs at ~30% rate: 1-2 chunks in flight
//   (1.5-3 KB/CU) vs the ~9 KB needed to cover ~900-cyc HBM-cold latency
//   (the 402 MB harness poison evicts L3 every iteration).  This version
//   issues ALL 24 x loads up front (P0..P3, 6 KB/CU in flight = the
//   structural max: a wave's entire x slice), then consumes chunks in load
//   order; the compiler's register deps generate vmcnt(18/12/6/0) waits.
//   W DMAs issued first so the manual vmcnt(24) retires exactly them.
//   Handoff + attention unchanged (harness-verified).
// ---------------------------------------------------------------------------
__global__ __launch_bounds__(1024, 4) void fused_kernel(
    const float* __restrict__ x, const unsigned short* __restrict__ WTf,
    float* __restrict__ out) {
  __shared__ __align__(16) unsigned short lds[73728];   // 147456 B
  const int tid = threadIdx.x, b = blockIdx.x;
  const int w = tid >> 6, lane = tid & 63;
  const int ln15 = lane & 15, quad = lane >> 4;

  // ---- 1. W frags -> LDS: async DMA, 9 x 1KB chunks per wave (issued 1st)
  {
    const uint4* src = (const uint4*)WTf;
    #pragma unroll
    for (int i = 0; i < 9; ++i) {
      int c = i * 1024 + tid;
      __builtin_amdgcn_global_load_lds(
          (const __attribute__((address_space(1))) unsigned*)(src + c),
          (__attribute__((address_space(3))) unsigned*)((char*)lds + (size_t)c * 16),
          16, 0, 0);
    }
  }
  __builtin_amdgcn_sched_barrier(0);   // pin: DMAs are the 9 OLDEST vmem ops

  const float* xr = x + (size_t)(b * 256 + w * 16 + ln15) * CDIM + quad * 8;

  // 4 chunk buffers, 3 ks each = 6 float4 apiece (96 VGPR total in flight)
  float4 P0[6], P1[6], P2[6], P3[6];

#define LOADST(BUF, BASE)                                                    \
  {                                                                          \
    _Pragma("unroll")                                                        \
    for (int j = 0; j < 3; ++j) {                                            \
      BUF[2 * j]     = *(const float4*)(xr + (BASE + j) * 32);               \
      BUF[2 * j + 1] = *(const float4*)(xr + (BASE + j) * 32 + 4);           \
    }                                                                        \
  }

#define USEST(BUF, BASE)                                                     \
  {                                                                          \
    _Pragma("unroll")                                                        \
    for (int k2 = 0; k2 < 3; ++k2) {                                         \
      float4 a0 = BUF[2 * k2], a1 = BUF[2 * k2 + 1];                         \
      bf16x8 t;                                                              \
      t[0] = (short)f2bf(a0.x); t[1] = (short)f2bf(a0.y);                    \
      t[2] = (short)f2bf(a0.z); t[3] = (short)f2bf(a0.w);                    \
      t[4] = (short)f2bf(a1.x); t[5] = (short)f2bf(a1.y);                    \
      t[6] = (short)f2bf(a1.z); t[7] = (short)f2bf(a1.w);                    \
      _Pragma("unroll")                                                      \
      for (int nt = 0; nt < 12; ++nt) {                                      \
        bf16x8 aw = *(const bf16x8*)&lds[(((BASE + k2) * 12 + nt) * 64 + lane) * 8]; \
        acc[nt] = __builtin_amdgcn_mfma_f32_16x16x32_bf16(aw, t, acc[nt], 0, 0, 0);  \
      }                                                                      \
    }                                                                        \
  }

  // ---- 2. issue the ENTIRE x slice: 24 loads in flight per wave ----------
  LOADST(P0, 0)
  LOADST(P1, 3)
  LOADST(P2, 6)
  LOADST(P3, 9)
  __builtin_amdgcn_sched_barrier(0);

  // counted wait: 9 DMA + 24 x-loads outstanding; vmcnt(24) retires exactly
  // the 9 oldest = all W DMAs.  Raw barrier (NOT __syncthreads: that would
  // drain vmcnt(0) and serialize the whole x stream behind it).
  asm volatile("s_waitcnt vmcnt(24)" ::: "memory");
  __builtin_amdgcn_s_barrier();
  __builtin_amdgcn_sched_barrier(0);

  // ---- 3. proj: consume chunks in load order (auto vmcnt 18/12/6/0) ------
  f32x4 acc[12];
  #pragma unroll
  for (int nt = 0; nt < 12; ++nt) acc[nt] = (f32x4){0.f, 0.f, 0.f, 0.f};

  USEST(P0, 0)
  USEST(P1, 3)
  USEST(P2, 6)
  USEST(P3, 9)

  __syncthreads();            // all waves done reading W -> LDS reusable

  // ---- 4. handoff: q/k/v -> LDS (aliased over the dead W region) ---------
  unsigned short (*QL)[72]  = (unsigned short(*)[72])lds;                 // 36864 B
  unsigned short (*KL)[72]  = (unsigned short(*)[72])(lds + 18432);       // 36864 B
  unsigned short (*VT)[264] = (unsigned short(*)[264])(lds + 36864);      // 33792 B
  unsigned short (*PL)[36]  = (unsigned short(*)[36])(lds + 53760 + w * 576); // 18432 B

  {
    const int trow = w * 16 + ln15;              // C-frag: t indexed by ln15
    #pragma unroll
    for (int nt = 0; nt < 4; ++nt) {             // q channels nt*16+quad*4..+3
      f32x4 a = acc[nt];
      unsigned p0 = f2bf(a[0]) | (f2bf(a[1]) << 16);
      unsigned p1 = f2bf(a[2]) | (f2bf(a[3]) << 16);
      *(uint2*)&QL[trow][nt * 16 + quad * 4] = (uint2){p0, p1};
    }
    #pragma unroll
    for (int nt = 4; nt < 8; ++nt) {             // k
      f32x4 a = acc[nt];
      unsigned p0 = f2bf(a[0]) | (f2bf(a[1]) << 16);
      unsigned p1 = f2bf(a[2]) | (f2bf(a[3]) << 16);
      *(uint2*)&KL[trow][(nt - 4) * 16 + quad * 4] = (uint2){p0, p1};
    }
    #pragma unroll
    for (int nt = 8; nt < 12; ++nt) {            // v, transposed into VT[h][t]
      f32x4 a = acc[nt];
      const int h = (nt - 8) * 16 + quad * 4;
      #pragma unroll
      for (int i = 0; i < 4; ++i)
        VT[h + i][trow] = (unsigned short)f2bf(a[i]);
    }
  }
  __syncthreads();

  // ---- 5. attention: wave w owns m-tile w --------------------------------
  {
    const int mt = w;
    const int t0 = mt * 16;
    const int NT = (mt | 1) + 1;                 // even # of 16-wide s-tiles

    bf16x8 aq[2];
    #pragma unroll
    for (int ks = 0; ks < 2; ++ks)
      aq[ks] = *(const bf16x8*)&QL[t0 + ln15][ks * 32 + quad * 8];

    float sv[16][4];
    #pragma unroll
    for (int nt = 0; nt < 16; ++nt) {
      if (nt < NT) {
        f32x4 a2 = (f32x4){0.f, 0.f, 0.f, 0.f};
        #pragma unroll
        for (int ks = 0; ks < 2; ++ks) {
          bf16x8 bf = *(const bf16x8*)&KL[nt * 16 + ln15][ks * 32 + quad * 8];
          a2 = __builtin_amdgcn_mfma_f32_16x16x32_bf16(aq[ks], bf, a2, 0, 0, 0);
        }
        int colg = nt * 16 + ln15;
        #pragma unroll
        for (int i = 0; i < 4; ++i) {
          int rowg = t0 + quad * 4 + i;
          sv[nt][i] = (colg <= rowg) ? a2[i] * 0.125f : -3.0e38f;   // 1/sqrt(64)
        }
      }
    }
    float mx[4] = {-3.0e38f, -3.0e38f, -3.0e38f, -3.0e38f};
    #pragma unroll
    for (int nt = 0; nt < 16; ++nt)
      if (nt < NT) {
        #pragma unroll
        for (int i = 0; i < 4; ++i) mx[i] = fmaxf(mx[i], sv[nt][i]);
      }
    #pragma unroll
    for (int i = 0; i < 4; ++i) {                // reduce across 16-lane group
      mx[i] = fmaxf(mx[i], __shfl_xor(mx[i], 8, 64));
      mx[i] = fmaxf(mx[i], __shfl_xor(mx[i], 4, 64));
      mx[i] = fmaxf(mx[i], __shfl_xor(mx[i], 2, 64));
      mx[i] = fmaxf(mx[i], __shfl_xor(mx[i], 1, 64));
    }
    float sm[4] = {0.f, 0.f, 0.f, 0.f};
    #pragma unroll
    for (int nt = 0; nt < 16; ++nt)
      if (nt < NT) {
        #pragma unroll
        for (int i = 0; i < 4; ++i) {
          float e = __expf(sv[nt][i] - mx[i]);
          sv[nt][i] = e;
          sm[i] += e;
        }
      }
    #pragma unroll
    for (int i = 0; i < 4; ++i) {
      sm[i] += __shfl_xor(sm[i], 8, 64);
      sm[i] += __shfl_xor(sm[i], 4, 64);
      sm[i] += __shfl_xor(sm[i], 2, 64);
      sm[i] += __shfl_xor(sm[i], 1, 64);
    }
    float inv[4];
    #pragma unroll
    for (int i = 0; i < 4; ++i) inv[i] = 1.0f / sm[i];

    // PV in 32-wide K chunks via the wave-private P buffer (DS in-order).
    f32x4 o[4];
    #pragma unroll
    for (int ont = 0; ont < 4; ++ont) o[ont] = (f32x4){0.f, 0.f, 0.f, 0.f};

    #pragma unroll
    for (int kc = 0; kc < 8; ++kc) {
      if (kc * 2 < NT) {
        #pragma unroll
        for (int half = 0; half < 2; ++half) {
          int nt = kc * 2 + half;
          #pragma unroll
          for (int i = 0; i < 4; ++i)
            PL[quad * 4 + i][half * 16 + ln15] =
                (unsigned short)f2bf(sv[nt][i] * inv[i]);
        }
        bf16x8 pa = *(const bf16x8*)&PL[ln15][quad * 8];
        #pragma unroll
        for (int ont = 0; ont < 4; ++ont) {
          bf16x8 vb = *(const bf16x8*)&VT[ont * 16 + ln15][kc * 32 + quad * 8];
          o[ont] = __builtin_amdgcn_mfma_f32_16x16x32_bf16(pa, vb, o[ont], 0, 0, 0);
        }
      }
    }

    #pragma unroll
    for (int ont = 0; ont < 4; ++ont) {
      int h = ont * 16 + ln15;
      #pragma unroll
      for (int i = 0; i < 4; ++i)
        out[(size_t)(b * 256 + t0 + quad * 4 + i) * HDIM + h] = o[ont][i];
    }
  }
}

// ---------------------------------------------------------------------------
// ws layout: only WTf (147456 B).
// ---------------------------------------------------------------------------
extern "C" void kernel_launch(void* const* d_in, const int* in_sizes, int n_in,
                              void* d_out, int out_size, void* d_ws, size_t ws_size,
                              hipStream_t stream) {
  const float* x  = (const float*)d_in[0];
  const float* Wk = (const float*)d_in[1];
  const float* Wq = (const float*)d_in[2];
  const float* Wv = (const float*)d_in[3];
  float* out = (float*)d_out;

  unsigned short* WTf = (unsigned short*)d_ws;   // 147456 B

  wtrans_kernel<<<(192 * CDIM + 255) / 256, 256, 0, stream>>>(Wk, Wq, Wv, WTf);
  fused_kernel<<<256, 1024, 0, stream>>>(x, WTf, out);
}

// Round 6
// 169.420 us; speedup vs baseline: 1.0320x; 1.0320x over previous
//
#include <hip/hip_runtime.h>

#define BATCH 256
#define SEQ   256
#define CDIM  384
#define HDIM  64

typedef __attribute__((ext_vector_type(8))) short bf16x8;
typedef __attribute__((ext_vector_type(4))) float f32x4;

__device__ __forceinline__ unsigned f2bf(float f) {
  union { float f; unsigned u; } v; v.f = f;
  unsigned r = v.u + 0x7FFFu + ((v.u >> 16) & 1u);   // RNE
  return r >> 16;
}

// ---------------------------------------------------------------------------
// kernel 0 (unchanged): WTf = [Wq|Wk|Wv]^T in MFMA fragment order.
//   frag record (ks,nt) = 64 lanes x 16 B; lane (ln15 + 16*quad) holds
//   WT row (nt*16+ln15), cols ks*32+quad*8 .. +7.
//   ks 0..5 = bytes [0,73728) (half 1), ks 6..11 = [73728,147456) (half 2).
// ---------------------------------------------------------------------------
__global__ void wtrans_kernel(const float* __restrict__ Wk, const float* __restrict__ Wq,
                              const float* __restrict__ Wv, unsigned short* __restrict__ WTf) {
  int gid = blockIdx.x * 256 + threadIdx.x;
  if (gid >= 192 * CDIM) return;
  int n = gid / CDIM, kk = gid - n * CDIM;
  const float* W = (n < 64) ? Wq : (n < 128) ? Wk : Wv;
  int nt = n >> 4, ln = n & 15, ks = kk >> 5, sub = (kk >> 3) & 3, j = kk & 7;
  int lane = ln + 16 * sub;
  WTf[(((size_t)ks * 12 + nt) * 64 + lane) * 8 + j] =
      (unsigned short)f2bf(W[kk * HDIM + (n & 63)]);
}

// ---------------------------------------------------------------------------
// kernel 1: fused proj+attention; x streamed via global_load_lds DMA.
//   Round-9 post-mortem: round-5's depth-2 schedule refilled the SAME buffer
//   it was reading in each PSTEP (race -> absmax 5.0).  This version is
//   depth-1: PSTEP(K) issues chunk K+1 into the OTHER buffer (whose last
//   read was consumed by PSTEP(K-1)'s MFMAs, i.e. provably complete), then
//   vmcnt(2) retires chunk K, then reads it.  Race-free by construction;
//   MLP comes from 16 waves x 2 KB in flight (~20 KB/CU > 9 KB needed).
//   Chunk offsets folded into the DMA pointer (no reliance on the builtin's
//   offset-immediate semantics).  W staged in halves (region A restaged once
//   behind barrier+vmcnt(0)+barrier).  x chunks XOR-swizzled via pre-swizzled
//   global source (linear DMA dest, same XOR on read) -> conflict-free reads.
//   LDS: W [0,73728) + x dbuf [73728,139264) = 139264 B; attn aliases after.
//   Handoff/attention/epilogue verbatim from the round-4 verified kernel.
// ---------------------------------------------------------------------------
__global__ __launch_bounds__(1024, 4) void fused_kernel(
    const float* __restrict__ x, const unsigned short* __restrict__ WTf,
    float* __restrict__ out) {
  __shared__ __align__(16) unsigned short lds[69632];   // 139264 B
  const int tid = threadIdx.x, b = blockIdx.x;
  const int w = tid >> 6, lane = tid & 63;
  const int ln15 = lane & 15, quad = lane >> 4;

  // ---- W half-1 DMAs (issued FIRST = oldest in the per-wave vmcnt FIFO) --
  // 72 records of 1024 B; waves 0-7 issue 5, waves 8-15 issue 4 (uniform).
  {
    #pragma unroll
    for (int i = 0; i < 5; ++i) {
      int m = i * 16 + w;
      if (m < 72) {
        int c = m * 64 + lane;
        __builtin_amdgcn_global_load_lds(
            (const __attribute__((address_space(1))) unsigned*)((const char*)WTf + (size_t)c * 16),
            (__attribute__((address_space(3))) unsigned*)((char*)lds + (size_t)c * 16),
            16, 0, 0);
      }
    }
  }
  __builtin_amdgcn_sched_barrier(0);

  // ---- x DMA addressing (XOR-swizzled global source, linear LDS dest) ----
  // chunk K = this wave's 16 rows x 32 k-floats = 2048 B, two 1024-B DMAs.
  // LDS slot G=j*64+lane holds row r=G>>3, col-group cg=(G&7)^(r&7).
  const int r0 = lane >> 3;                       // rows 0..7 (j=0), +8 (j=1)
  const int cgs = (lane & 7) ^ r0;                // swizzled col-group
  const char* xs0 = (const char*)x +
      ((size_t)(b * 256 + w * 16 + r0) * CDIM + cgs * 4) * 4;
  const char* xs1 = xs0 + (size_t)8 * CDIM * 4;   // rows +8, same swizzle
  char* xld = (char*)lds + 73728 + w * 4096 + lane * 16;

#define XDMA(K, S)                                                            \
  __builtin_amdgcn_global_load_lds(                                           \
      (const __attribute__((address_space(1))) unsigned*)(xs0 + (K) * 128),   \
      (__attribute__((address_space(3))) unsigned*)(xld + (S) * 2048),        \
      16, 0, 0);                                                              \
  __builtin_amdgcn_global_load_lds(                                           \
      (const __attribute__((address_space(1))) unsigned*)(xs1 + (K) * 128),   \
      (__attribute__((address_space(3))) unsigned*)(xld + (S) * 2048 + 1024), \
      16, 0, 0);

  // prologue: chunk 0 in flight behind the W half-1 DMAs
  XDMA(0, 0)
  __builtin_amdgcn_sched_barrier(0);
  // retires all W half-1 DMAs (the oldest 4/5), leaves chunk 0 in flight.
  asm volatile("s_waitcnt vmcnt(2)" ::: "memory");
  __builtin_amdgcn_s_barrier();
  __builtin_amdgcn_sched_barrier(0);

  // read offsets within a chunk (XOR matches the DMA source swizzle)
  const int roA = ln15 * 128 + (((2 * quad) ^ (ln15 & 7)) * 16);
  const int roB = ln15 * 128 + ((((2 * quad) + 1) ^ (ln15 & 7)) * 16);

  f32x4 acc[12];
  #pragma unroll
  for (int nt = 0; nt < 12; ++nt) acc[nt] = (f32x4){0.f, 0.f, 0.f, 0.f};

  // PSTEP(K): issue chunk K+1 (other buffer), retire chunk K, read, MFMA.
#define PSTEP(K, KIDX, VMN, ISSUE)                                            \
  {                                                                           \
    ISSUE                                                                     \
    __builtin_amdgcn_sched_barrier(0);                                        \
    asm volatile("s_waitcnt vmcnt(" #VMN ")" ::: "memory");                   \
    __builtin_amdgcn_sched_barrier(0);                                        \
    const char* cb = (const char*)lds + 73728 + w * 4096 + ((K) & 1) * 2048;  \
    float4 fa = *(const float4*)(cb + roA);                                   \
    float4 fb = *(const float4*)(cb + roB);                                   \
    bf16x8 t;                                                                 \
    t[0] = (short)f2bf(fa.x); t[1] = (short)f2bf(fa.y);                       \
    t[2] = (short)f2bf(fa.z); t[3] = (short)f2bf(fa.w);                       \
    t[4] = (short)f2bf(fb.x); t[5] = (short)f2bf(fb.y);                       \
    t[6] = (short)f2bf(fb.z); t[7] = (short)f2bf(fb.w);                       \
    _Pragma("unroll")                                                         \
    for (int nt = 0; nt < 12; ++nt) {                                         \
      bf16x8 aw = *(const bf16x8*)&lds[(((KIDX) * 12 + nt) * 64 + lane) * 8]; \
      acc[nt] = __builtin_amdgcn_mfma_f32_16x16x32_bf16(aw, t, acc[nt], 0, 0, 0); \
    }                                                                         \
  }

  PSTEP(0, 0, 2, XDMA(1, 1))
  PSTEP(1, 1, 2, XDMA(2, 0))
  PSTEP(2, 2, 2, XDMA(3, 1))
  PSTEP(3, 3, 2, XDMA(4, 0))
  PSTEP(4, 4, 2, XDMA(5, 1))
  PSTEP(5, 5, 2, XDMA(6, 0))

  // ---- W half-2 swap: half-1 reads are all register-consumed (MFMAs of
  // PSTEP(5) issued before we reach the barrier), so region A is dead.
  __builtin_amdgcn_sched_barrier(0);
  __builtin_amdgcn_s_barrier();
  {
    #pragma unroll
    for (int i = 0; i < 5; ++i) {
      int m = i * 16 + w;
      if (m < 72) {
        int c = m * 64 + lane;
        __builtin_amdgcn_global_load_lds(
            (const __attribute__((address_space(1))) unsigned*)((const char*)WTf + 73728 + (size_t)c * 16),
            (__attribute__((address_space(3))) unsigned*)((char*)lds + (size_t)c * 16),
            16, 0, 0);
      }
    }
  }
  asm volatile("s_waitcnt vmcnt(0)" ::: "memory");   // lands W2 + chunk 6
  __builtin_amdgcn_s_barrier();
  __builtin_amdgcn_sched_barrier(0);

  PSTEP(6,  0, 2, XDMA(7, 1))
  PSTEP(7,  1, 2, XDMA(8, 0))
  PSTEP(8,  2, 2, XDMA(9, 1))
  PSTEP(9,  3, 2, XDMA(10, 0))
  PSTEP(10, 4, 2, XDMA(11, 1))
  PSTEP(11, 5, 0, )

  __syncthreads();            // all waves done -> LDS reusable for attn

  // ---- handoff: q/k/v -> LDS (aliased over the dead W/x regions) ---------
  unsigned short (*QL)[72]  = (unsigned short(*)[72])lds;                 // 36864 B
  unsigned short (*KL)[72]  = (unsigned short(*)[72])(lds + 18432);       // 36864 B
  unsigned short (*VT)[264] = (unsigned short(*)[264])(lds + 36864);      // 33792 B
  unsigned short (*PL)[36]  = (unsigned short(*)[36])(lds + 53760 + w * 576); // 18432 B

  {
    const int trow = w * 16 + ln15;              // C-frag: t indexed by ln15
    #pragma unroll
    for (int nt = 0; nt < 4; ++nt) {             // q channels nt*16+quad*4..+3
      f32x4 a = acc[nt];
      unsigned p0 = f2bf(a[0]) | (f2bf(a[1]) << 16);
      unsigned p1 = f2bf(a[2]) | (f2bf(a[3]) << 16);
      *(uint2*)&QL[trow][nt * 16 + quad * 4] = (uint2){p0, p1};
    }
    #pragma unroll
    for (int nt = 4; nt < 8; ++nt) {             // k
      f32x4 a = acc[nt];
      unsigned p0 = f2bf(a[0]) | (f2bf(a[1]) << 16);
      unsigned p1 = f2bf(a[2]) | (f2bf(a[3]) << 16);
      *(uint2*)&KL[trow][(nt - 4) * 16 + quad * 4] = (uint2){p0, p1};
    }
    #pragma unroll
    for (int nt = 8; nt < 12; ++nt) {            // v, transposed into VT[h][t]
      f32x4 a = acc[nt];
      const int h = (nt - 8) * 16 + quad * 4;
      #pragma unroll
      for (int i = 0; i < 4; ++i)
        VT[h + i][trow] = (unsigned short)f2bf(a[i]);
    }
  }
  __syncthreads();

  // ---- attention: wave w owns m-tile w (verbatim, harness-verified) ------
  {
    const int mt = w;
    const int t0 = mt * 16;
    const int NT = (mt | 1) + 1;                 // even # of 16-wide s-tiles

    bf16x8 aq[2];
    #pragma unroll
    for (int ks = 0; ks < 2; ++ks)
      aq[ks] = *(const bf16x8*)&QL[t0 + ln15][ks * 32 + quad * 8];

    float sv[16][4];
    #pragma unroll
    for (int nt = 0; nt < 16; ++nt) {
      if (nt < NT) {
        f32x4 a2 = (f32x4){0.f, 0.f, 0.f, 0.f};
        #pragma unroll
        for (int ks = 0; ks < 2; ++ks) {
          bf16x8 bf = *(const bf16x8*)&KL[nt * 16 + ln15][ks * 32 + quad * 8];
          a2 = __builtin_amdgcn_mfma_f32_16x16x32_bf16(aq[ks], bf, a2, 0, 0, 0);
        }
        int colg = nt * 16 + ln15;
        #pragma unroll
        for (int i = 0; i < 4; ++i) {
          int rowg = t0 + quad * 4 + i;
          sv[nt][i] = (colg <= rowg) ? a2[i] * 0.125f : -3.0e38f;   // 1/sqrt(64)
        }
      }
    }
    float mx[4] = {-3.0e38f, -3.0e38f, -3.0e38f, -3.0e38f};
    #pragma unroll
    for (int nt = 0; nt < 16; ++nt)
      if (nt < NT) {
        #pragma unroll
        for (int i = 0; i < 4; ++i) mx[i] = fmaxf(mx[i], sv[nt][i]);
      }
    #pragma unroll
    for (int i = 0; i < 4; ++i) {                // reduce across 16-lane group
      mx[i] = fmaxf(mx[i], __shfl_xor(mx[i], 8, 64));
      mx[i] = fmaxf(mx[i], __shfl_xor(mx[i], 4, 64));
      mx[i] = fmaxf(mx[i], __shfl_xor(mx[i], 2, 64));
      mx[i] = fmaxf(mx[i], __shfl_xor(mx[i], 1, 64));
    }
    float sm[4] = {0.f, 0.f, 0.f, 0.f};
    #pragma unroll
    for (int nt = 0; nt < 16; ++nt)
      if (nt < NT) {
        #pragma unroll
        for (int i = 0; i < 4; ++i) {
          float e = __expf(sv[nt][i] - mx[i]);
          sv[nt][i] = e;
          sm[i] += e;
        }
      }
    #pragma unroll
    for (int i = 0; i < 4; ++i) {
      sm[i] += __shfl_xor(sm[i], 8, 64);
      sm[i] += __shfl_xor(sm[i], 4, 64);
      sm[i] += __shfl_xor(sm[i], 2, 64);
      sm[i] += __shfl_xor(sm[i], 1, 64);
    }
    float inv[4];
    #pragma unroll
    for (int i = 0; i < 4; ++i) inv[i] = 1.0f / sm[i];

    // PV in 32-wide K chunks via the wave-private P buffer (DS in-order).
    f32x4 o[4];
    #pragma unroll
    for (int ont = 0; ont < 4; ++ont) o[ont] = (f32x4){0.f, 0.f, 0.f, 0.f};

    #pragma unroll
    for (int kc = 0; kc < 8; ++kc) {
      if (kc * 2 < NT) {
        #pragma unroll
        for (int half = 0; half < 2; ++half) {
          int nt = kc * 2 + half;
          #pragma unroll
          for (int i = 0; i < 4; ++i)
            PL[quad * 4 + i][half * 16 + ln15] =
                (unsigned short)f2bf(sv[nt][i] * inv[i]);
        }
        bf16x8 pa = *(const bf16x8*)&PL[ln15][quad * 8];
        #pragma unroll
        for (int ont = 0; ont < 4; ++ont) {
          bf16x8 vb = *(const bf16x8*)&VT[ont * 16 + ln15][kc * 32 + quad * 8];
          o[ont] = __builtin_amdgcn_mfma_f32_16x16x32_bf16(pa, vb, o[ont], 0, 0, 0);
        }
      }
    }

    #pragma unroll
    for (int ont = 0; ont < 4; ++ont) {
      int h = ont * 16 + ln15;
      #pragma unroll
      for (int i = 0; i < 4; ++i)
        out[(size_t)(b * 256 + t0 + quad * 4 + i) * HDIM + h] = o[ont][i];
    }
  }
}

// ---------------------------------------------------------------------------
// ws layout: only WTf (147456 B).
// ---------------------------------------------------------------------------
extern "C" void kernel_launch(void* const* d_in, const int* in_sizes, int n_in,
                              void* d_out, int out_size, void* d_ws, size_t ws_size,
                              hipStream_t stream) {
  const float* x  = (const float*)d_in[0];
  const float* Wk = (const float*)d_in[1];
  const float* Wq = (const float*)d_in[2];
  const float* Wv = (const float*)d_in[3];
  float* out = (float*)d_out;

  unsigned short* WTf = (unsigned short*)d_ws;   // 147456 B

  wtrans_kernel<<<(192 * CDIM + 255) / 256, 256, 0, stream>>>(Wk, Wq, Wv, WTf);
  fused_kernel<<<256, 1024, 0, stream>>>(x, WTf, out);
}